// Round 9
// baseline (207.676 us; speedup 1.0000x reference)
//
#include <hip/hip_runtime.h>
#include <stdint.h>

// SparseConv3d bf16-MFMA implicit GEMM. B=2, Cin=32, Cout=64, D=64, K=3.
// Round 9: z-walk deep pipeline. Block = 4y x 64x x 64co, walks 8 z-slices.
//   LDS = 4-slab ring (slab = 6 padded y-rows x 4224B = 25.3KB; 101KB total,
//   1 block/CU, 8 waves). Step s: stage plane z+2 (global_load_lds, in flight
//   the whole step), compute output z from resident planes z-1,z,z+1
//   (6 phases: 3 zr x 2 cb; per phase 9 wf L1-hot loads + 12 ds_read_b128 +
//   18 MFMA with setprio), epilogue store, ONE barrier. Staging amortized 3x
//   vs rounds 6/7; weights z-invariant -> L1-resident.
// xt layout: [b][zz(64)][yy(66 padded)] rows of 66 x-slots * 64B. Interior
//   slot sx = x+1; 16B chunk c = ci>>3 stored at c ^ k(sx), k = ((x>>1)^(x>>3))&3
//   (bank swizzle baked into global layout; slots 0,65 and pad rows all-zero).

#define DD 64
#define CIN 32
#define COUT 64

typedef __bf16 bf16x8 __attribute__((ext_vector_type(8)));
typedef float f32x16 __attribute__((ext_vector_type(16)));

#define ROW_U16   2112u                                // 66 slots * 32 ci
#define ROW_B     4224u
#define SLAB_B    25344u                               // 6 rows
#define XT_U16    ((size_t)2 * 64 * 66 * ROW_U16)
#define XT_BYTES  (XT_U16 * 2)                         // 35,684,352
#define WPK_U16   (27 * 2 * 2 * 64 * 8)                // 55,296
#define WPK_BYTES ((size_t)WPK_U16 * 2)
#define ZP_BYTES  ((size_t)SLAB_B)                     // zero slab for z-OOB
#define WS_NEEDED (XT_BYTES + WPK_BYTES + ZP_BYTES)
#define CONV_LDS  (4 * 25344)                          // 101,376 B

__device__ __forceinline__ uint16_t f2bf(float f) {
    uint32_t u = __builtin_bit_cast(uint32_t, f);
    u += 0x7fffu + ((u >> 16) & 1u);   // RNE
    return (uint16_t)(u >> 16);
}

__device__ __forceinline__ void gll16(const void* g, void* l) {
    __builtin_amdgcn_global_load_lds(
        (__attribute__((address_space(1))) void*)g,
        (__attribute__((address_space(3))) void*)l, 16, 0, 0);
}

// ---------------- pre-kernel 1: weight pack + zero slab ----------------
// wpk flat: (((k27*2 + cb)*2 + ct)*64 + lane)*8 + j
//   lane holds A[co = ct*32 + (lane&31)][ci = cb*16 + (lane>>5)*8 + j]
__global__ void pack_weights(const float* __restrict__ w, uint16_t* __restrict__ wpk,
                             uint4* __restrict__ zp) {
    int flat = blockIdx.x * 256 + threadIdx.x;
    if (flat < WPK_U16) {
        int j   = flat & 7;
        int l   = (flat >> 3) & 63;
        int ct  = (flat >> 9) & 1;
        int cb  = (flat >> 10) & 1;
        int k27 = flat >> 11;
        int co = ct * 32 + (l & 31);
        int ci = cb * 16 + ((l >> 5) * 8) + j;
        wpk[flat] = f2bf(w[(co * CIN + ci) * 27 + k27]);
    } else if (flat - WPK_U16 < (int)(ZP_BYTES / 16)) {
        zp[flat - WPK_U16] = make_uint4(0, 0, 0, 0);
    }
}

// ---------------- pre-kernel 2: x -> padded channel-last swizzled bf16 ----------------
// grid (66, 64, 2): one (b, z, yy) padded row per block. yy = 0/65 zero rows;
// interior: slot sx = x+1, chunk c=ci>>3 at c ^ (((x>>1)^(x>>3))&3); slots 0,65 zero.
__global__ __launch_bounds__(256)
void transpose_x(const float* __restrict__ x, uint16_t* __restrict__ xt) {
    __shared__ uint16_t tile[ROW_U16];
    const int yy = blockIdx.x, z = blockIdx.y, b = blockIdx.z;
    const int y = yy - 1;
    const int t = threadIdx.x;
    uint4* dst = (uint4*)(xt + ((size_t)(b * DD + z) * 66 + yy) * ROW_U16);

    if (y < 0 || y >= DD) {
        for (int i = t; i < 264; i += 256) dst[i] = make_uint4(0, 0, 0, 0);
        return;
    }
    const int ci = t >> 3;
    const int xs = (t & 7) * 8;
    const float* src = x + ((((size_t)b * CIN + ci) * DD + z) * DD + y) * DD + xs;
    float4 v0 = *(const float4*)src;
    float4 v1 = *(const float4*)(src + 4);
    float vals[8] = {v0.x, v0.y, v0.z, v0.w, v1.x, v1.y, v1.z, v1.w};
#pragma unroll
    for (int e = 0; e < 8; ++e) {
        const int xv = xs + e;
        const int k = ((xv >> 1) ^ (xv >> 3)) & 3;
        const int pos = (xv + 1) * 32 + (((ci >> 3) ^ k) << 3) + (ci & 7);
        tile[pos] = f2bf(vals[e]);
    }
    if (t < 32) { tile[t] = 0; tile[65 * 32 + t] = 0; }   // x-pad slots
    __syncthreads();
    for (int i = t; i < 264; i += 256) dst[i] = ((const uint4*)tile)[i];
}

// ---------------- main kernel: z-walk MFMA conv ----------------
// grid (16, 8, 2) = 256 blocks x 512 thr (8 waves: w = wy*4 + xtile*2 + ct).
__global__ __launch_bounds__(512, 2)
void conv_mfma(const uint16_t* __restrict__ xt, const uint16_t* __restrict__ wpk,
               const uint16_t* __restrict__ zp,
               const int* __restrict__ mask, const float* __restrict__ bias,
               float* __restrict__ out) {
    extern __shared__ __align__(16) unsigned char lds[];   // 4 slabs x 25344
    const int yqi = blockIdx.x;      // y-quad: y0 = 4*yqi
    const int zq  = blockIdx.y;      // z-octet: z0 = 8*zq
    const int b   = blockIdx.z;
    const int y0 = yqi * 4;
    const int z0 = zq * 8;
    const int tid = threadIdx.x;
    const int lane = tid & 63;
    const int w = __builtin_amdgcn_readfirstlane(tid >> 6);
    const int ct    = w & 1;
    const int xtile = (w >> 1) & 1;
    const int wy    = w >> 2;        // 0/1: which y-pair
    const int u = lane & 31;
    const int h = lane >> 5;
    const int xoff = xtile * 32;

    // stage one z-plane slab (6 rows, 25344B) into ring slab; OOB -> zero page
    auto STAGE = [&](int zz, unsigned slab) {
        const uint16_t* sb = (zz >= 0 && zz < DD)
            ? xt + ((size_t)(b * DD + zz) * 66 + y0) * ROW_U16
            : zp;
#pragma unroll
        for (int it = 0; it < 3; ++it)
            gll16(sb + it * 4096 + w * 512 + lane * 8,
                  &lds[slab + (unsigned)it * 8192u + (unsigned)w * 1024u]);
        if (w == 0 && lane < 48)                       // 768B tail
            gll16(sb + 12288 + lane * 8, &lds[slab + 24576u]);
    };

    // bias for this wave's 16 C-rows (z-invariant) -> regs
    float bv[16];
#pragma unroll
    for (int r = 0; r < 16; ++r)
        bv[r] = bias[ct * 32 + (r & 3) + 8 * (r >> 2) + 4 * h];

    // prologue: planes z0-1, z0, z0+1 -> slabs 0,1,2
    STAGE(z0 - 1, 0u);
    STAGE(z0,     SLAB_B);
    STAGE(z0 + 1, 2u * SLAB_B);
    __syncthreads();

    for (int s = 0; s < 8; ++s) {
        if (s <= 6) STAGE(z0 + s + 2, (unsigned)((s + 3) & 3) * SLAB_B);

        f32x16 acc0 = {}, acc1 = {};   // y = y0+2wy, y0+2wy+1

#pragma unroll
        for (int zr = 0; zr < 3; ++zr) {
            const unsigned slab = (unsigned)((s + zr) & 3) * SLAB_B;
#pragma unroll
            for (int cbp = 0; cbp < 2; ++cbp) {
                bf16x8 wf[9];
#pragma unroll
                for (int q = 0; q < 9; ++q)
                    wf[q] = *(const bf16x8*)(wpk
                        + (size_t)(((zr * 9 + q) * 2 + cbp) * 2 + ct) * 512 + lane * 8);
                const unsigned cc = (unsigned)(cbp * 2 + h);
                bf16x8 bf[4][3];
#pragma unroll
                for (int rr = 0; rr < 4; ++rr) {
                    const unsigned rowb = slab + (unsigned)(2 * wy + rr) * ROW_B;
#pragma unroll
                    for (int kx = 0; kx < 3; ++kx) {
                        const unsigned sx = (unsigned)(xoff + u + kx);
                        const unsigned k = (((sx - 1u) >> 1) ^ ((sx - 1u) >> 3)) & 3u;
                        bf[rr][kx] = *(const bf16x8*)&lds[rowb + sx * 64u + ((cc ^ k) << 4)];
                    }
                }
                __builtin_amdgcn_s_setprio(1);
#pragma unroll
                for (int rr = 0; rr < 4; ++rr) {
#pragma unroll
                    for (int kx = 0; kx < 3; ++kx) {
                        if (rr <= 2)            // ly=0, ky=rr
                            acc0 = __builtin_amdgcn_mfma_f32_32x32x16_bf16(
                                wf[rr * 3 + kx], bf[rr][kx], acc0, 0, 0, 0);
                        if (rr >= 1)            // ly=1, ky=rr-1
                            acc1 = __builtin_amdgcn_mfma_f32_32x32x16_bf16(
                                wf[(rr - 1) * 3 + kx], bf[rr][kx], acc1, 0, 0, 0);
                    }
                }
                __builtin_amdgcn_s_setprio(0);
            }
        }

        // epilogue for z = z0+s: +bias, x mask, store
        const int zc = z0 + s;
        const int ya = y0 + 2 * wy;
        const size_t mb = (((size_t)b * DD + zc) * DD + ya) * DD + xoff + u;
        const float m0 = mask[mb]      ? 1.0f : 0.0f;
        const float m1 = mask[mb + DD] ? 1.0f : 0.0f;
#pragma unroll
        for (int r = 0; r < 16; ++r) {
            const int co = ct * 32 + (r & 3) + 8 * (r >> 2) + 4 * h;
            const size_t o = ((size_t)(b * COUT + co) * DD + zc) * (DD * DD)
                           + (size_t)ya * DD + xoff + u;
            out[o]      = (acc0[r] + bv[r]) * m0;
            out[o + DD] = (acc1[r] + bv[r]) * m1;
        }

        __syncthreads();   // stage(s+2) resident; slab (s)&3 free for reuse
    }
}

// ---------------- fp32 fallback (ws too small) ----------------
#define CI_BLK 16
__global__ __launch_bounds__(256, 2)
void sparse_conv3d_f32(const float* __restrict__ x,
                       const int* __restrict__ mask,
                       const float* __restrict__ weight,
                       const float* __restrict__ bias,
                       float* __restrict__ out) {
    __shared__ float lds[9 * CI_BLK * 66];
    const int y = blockIdx.x, z = blockIdx.y, b = blockIdx.z;
    const int lane = threadIdx.x & 63;
    const int wave = __builtin_amdgcn_readfirstlane(threadIdx.x >> 6);
    float acc[16];
#pragma unroll
    for (int j = 0; j < 16; ++j) acc[j] = 0.0f;
    const int co0 = wave * 16;
    const float* wbase = weight + (size_t)co0 * (CIN * 27);
    for (int cbl = 0; cbl < 2; ++cbl) {
        if (cbl) __syncthreads();
        for (int i = wave; i < 9 * CI_BLK; i += 4) {
            const int r = i >> 4, ci_l = i & 15;
            const int zz = z + (r / 3) - 1, yy = y + (r % 3) - 1;
            const int ci = cbl * CI_BLK + ci_l;
            float v = 0.0f;
            if (zz >= 0 && zz < DD && yy >= 0 && yy < DD)
                v = x[((((size_t)b * CIN + ci) * DD + zz) * DD + yy) * DD + lane];
            float* row = &lds[(size_t)i * 66];
            row[1 + lane] = v;
            if (lane == 0) { row[0] = 0.0f; row[65] = 0.0f; }
        }
        __syncthreads();
        for (int ci_l = 0; ci_l < CI_BLK; ++ci_l) {
            const int ci = cbl * CI_BLK + ci_l;
#pragma unroll
            for (int kz = 0; kz < 3; ++kz) {
#pragma unroll
                for (int ky = 0; ky < 3; ++ky) {
                    const int r = kz * 3 + ky;
                    const float* xrow = &lds[(size_t)(r * CI_BLK + ci_l) * 66 + lane];
                    const float xv0 = xrow[0], xv1 = xrow[1], xv2 = xrow[2];
                    const float* wp = wbase + ci * 27 + kz * 9 + ky * 3;
#pragma unroll
                    for (int j = 0; j < 16; ++j) {
                        acc[j] += wp[(size_t)j * (CIN * 27) + 0] * xv0
                                + wp[(size_t)j * (CIN * 27) + 1] * xv1
                                + wp[(size_t)j * (CIN * 27) + 2] * xv2;
                    }
                }
            }
        }
    }
    const float m = mask[(((size_t)b * DD + z) * DD + y) * DD + lane] ? 1.0f : 0.0f;
#pragma unroll
    for (int j = 0; j < 16; ++j) {
        const int co = co0 + j;
        out[((((size_t)b * COUT + co) * DD + z) * DD + y) * DD + lane] = (acc[j] + bias[co]) * m;
    }
}
#undef CI_BLK

extern "C" void kernel_launch(void* const* d_in, const int* in_sizes, int n_in,
                              void* d_out, int out_size, void* d_ws, size_t ws_size,
                              hipStream_t stream) {
    const float* x    = (const float*)d_in[0];
    const int*   mask = (const int*)d_in[1];
    const float* w    = (const float*)d_in[2];
    const float* bias = (const float*)d_in[3];
    float*       out  = (float*)d_out;

    if (ws_size < WS_NEEDED) {
        sparse_conv3d_f32<<<dim3(DD, DD, 2), 256, 0, stream>>>(x, mask, w, bias, out);
        return;
    }

    uint16_t* xt  = (uint16_t*)d_ws;
    uint16_t* wpk = (uint16_t*)((char*)d_ws + XT_BYTES);
    uint16_t* zp  = (uint16_t*)((char*)d_ws + XT_BYTES + WPK_BYTES);

    pack_weights<<<(WPK_U16 + (int)(ZP_BYTES / 16) + 255) / 256, 256, 0, stream>>>(w, wpk, (uint4*)zp);
    transpose_x<<<dim3(66, DD, 2), 256, 0, stream>>>(x, xt);
    conv_mfma<<<dim3(16, 8, 2), 512, CONV_LDS, stream>>>(xt, wpk, zp, mask, bias, out);
}

// Round 10
// 108.586 us; speedup vs baseline: 1.9125x; 1.9125x over previous
//
#include <hip/hip_runtime.h>
#include <stdint.h>

// SparseConv3d bf16-MFMA implicit GEMM. B=2, Cin=32, Cout=64, D=64, K=3.
// Round 10: ratio fix. Rounds 3-7 all plateaued at MfmaUtil 25-29% because
//   MFMA:ds_read_b128 = 2 caps MfmaUtil at ~33% (LDS pipe: ~10-12 cyc/b128 vs
//   MFMA wall 2 cyc/CU). This round: wave = 2y x 32x x 64co (BOTH co-halves)
//   -> 36 MFMA : 12 ds_read per phase (ratio 3). Macro-shape = round 6/7
//   (the best): 256-thr/4-wave blocks (wy x xtile), y-quad tile, 18-row LDS
//   76KB, 2 blocks/CU, one z per block (z-neighbors land on same XCD -> L2
//   absorbs the 3x z-overlap; r6 measured FETCH=26MB), gll16 slab staging,
//   2 barriers/block. acc 64 VGPR; launch_bounds(256,2).
// xt layout (r9 padded): [b][zz(64)][yy(66 padded)] rows of 66 x-slots * 64B.
//   Interior slot sx = x+1; 16B chunk c = ci>>3 stored at c ^ ((x>>1)&3)
//   (r6/r7 key: bank-enumeration conflict-free for all kx shifts; the r9
//   ((x>>1)^(x>>3))&3 key has an 8-lane collision at kx=1 -> reverted).

#define DD 64
#define CIN 32
#define COUT 64

typedef __bf16 bf16x8 __attribute__((ext_vector_type(8)));
typedef float f32x16 __attribute__((ext_vector_type(16)));

#define ROW_U16   2112u                                // 66 slots * 32 ci
#define ROW_B     4224u
#define SLAB_B    25344u                               // 6 y-rows
#define XT_U16    ((size_t)2 * 64 * 66 * ROW_U16)
#define XT_BYTES  (XT_U16 * 2)                         // 35,684,352
#define WPK_U16   (27 * 2 * 2 * 64 * 8)                // 55,296
#define WPK_BYTES ((size_t)WPK_U16 * 2)
#define ZP_BYTES  ((size_t)SLAB_B)                     // zero slab for z-OOB
#define WS_NEEDED (XT_BYTES + WPK_BYTES + ZP_BYTES)
#define CONV_LDS  (3 * 25344)                          // 76,032 B

__device__ __forceinline__ uint16_t f2bf(float f) {
    uint32_t u = __builtin_bit_cast(uint32_t, f);
    u += 0x7fffu + ((u >> 16) & 1u);   // RNE
    return (uint16_t)(u >> 16);
}

__device__ __forceinline__ void gll16(const void* g, void* l) {
    __builtin_amdgcn_global_load_lds(
        (__attribute__((address_space(1))) void*)g,
        (__attribute__((address_space(3))) void*)l, 16, 0, 0);
}

// ---------------- pre-kernel 1: weight pack + zero slab ----------------
// wpk flat: (((k27*2 + cb)*2 + ct)*64 + lane)*8 + j
//   lane holds A[co = ct*32 + (lane&31)][ci = cb*16 + (lane>>5)*8 + j]
__global__ void pack_weights(const float* __restrict__ w, uint16_t* __restrict__ wpk,
                             uint4* __restrict__ zp) {
    int flat = blockIdx.x * 256 + threadIdx.x;
    if (flat < WPK_U16) {
        int j   = flat & 7;
        int l   = (flat >> 3) & 63;
        int ct  = (flat >> 9) & 1;
        int cb  = (flat >> 10) & 1;
        int k27 = flat >> 11;
        int co = ct * 32 + (l & 31);
        int ci = cb * 16 + ((l >> 5) * 8) + j;
        wpk[flat] = f2bf(w[(co * CIN + ci) * 27 + k27]);
    } else if (flat - WPK_U16 < (int)(ZP_BYTES / 16)) {
        zp[flat - WPK_U16] = make_uint4(0, 0, 0, 0);
    }
}

// ---------------- pre-kernel 2: x -> padded channel-last swizzled bf16 ----------------
// grid (66, 64, 2): one (b, z, yy) padded row per block. yy = 0/65 zero rows;
// interior: slot sx = x+1, chunk c=ci>>3 at c ^ ((x>>1)&3); slots 0,65 zero.
__global__ __launch_bounds__(256)
void transpose_x(const float* __restrict__ x, uint16_t* __restrict__ xt) {
    __shared__ uint16_t tile[ROW_U16];
    const int yy = blockIdx.x, z = blockIdx.y, b = blockIdx.z;
    const int y = yy - 1;
    const int t = threadIdx.x;
    uint4* dst = (uint4*)(xt + ((size_t)(b * DD + z) * 66 + yy) * ROW_U16);

    if (y < 0 || y >= DD) {
        for (int i = t; i < 264; i += 256) dst[i] = make_uint4(0, 0, 0, 0);
        return;
    }
    const int ci = t >> 3;
    const int xs = (t & 7) * 8;
    const float* src = x + ((((size_t)b * CIN + ci) * DD + z) * DD + y) * DD + xs;
    float4 v0 = *(const float4*)src;
    float4 v1 = *(const float4*)(src + 4);
    float vals[8] = {v0.x, v0.y, v0.z, v0.w, v1.x, v1.y, v1.z, v1.w};
#pragma unroll
    for (int e = 0; e < 8; ++e) {
        const int xv = xs + e;
        const int k = (xv >> 1) & 3;
        const int pos = (xv + 1) * 32 + (((ci >> 3) ^ k) << 3) + (ci & 7);
        tile[pos] = f2bf(vals[e]);
    }
    if (t < 32) { tile[t] = 0; tile[65 * 32 + t] = 0; }   // x-pad slots
    __syncthreads();
    for (int i = t; i < 264; i += 256) dst[i] = ((const uint4*)tile)[i];
}

// ---------------- main kernel ----------------
// grid (16 yq, 64 z, 2 b) x 256 thr = 4 waves: xtile = w&1, wy = w>>1.
// Wave: 2y x 32x x 64co. Per phase (zr,cb): 18 wf loads, 12 ds_read, 36 MFMA.
__global__ __launch_bounds__(256, 2)
void conv_mfma(const uint16_t* __restrict__ xt, const uint16_t* __restrict__ wpk,
               const uint16_t* __restrict__ zp,
               const int* __restrict__ mask, const float* __restrict__ bias,
               float* __restrict__ out) {
    extern __shared__ __align__(16) unsigned char lds[];   // 3 slabs x 25344
    const int yq = blockIdx.x, z = blockIdx.y, b = blockIdx.z;
    const int y0 = yq * 4;
    const int tid = threadIdx.x;
    const int lane = tid & 63;
    const int w = __builtin_amdgcn_readfirstlane(tid >> 6);
    const int xtile = w & 1;
    const int wy    = w >> 1;
    const int u = lane & 31;
    const int h = lane >> 5;
    const int xoff = xtile * 32;

    // ---- stage 3 z-plane slabs (6 padded y-rows each); OOB -> zero slab ----
#pragma unroll
    for (int p = 0; p < 3; ++p) {
        const int zz = z - 1 + p;
        const uint16_t* sb = (zz >= 0 && zz < DD)
            ? xt + ((size_t)(b * DD + zz) * 66 + y0) * ROW_U16
            : zp;
        const unsigned slab = (unsigned)p * SLAB_B;
#pragma unroll
        for (int it = 0; it < 6; ++it)
            gll16(sb + it * 2048 + w * 512 + lane * 8,
                  &lds[slab + (unsigned)it * 4096u + (unsigned)w * 1024u]);
        if (w == 3 && lane < 48)                       // 768B tail
            gll16(sb + 12288 + lane * 8, &lds[slab + 24576u]);
    }
    __syncthreads();

    f32x16 acc[2][2];   // [ly][ct]
#pragma unroll
    for (int ly = 0; ly < 2; ++ly)
#pragma unroll
        for (int ct = 0; ct < 2; ++ct)
#pragma unroll
            for (int i = 0; i < 16; ++i) acc[ly][ct][i] = 0.f;

#pragma unroll
    for (int zr = 0; zr < 3; ++zr) {
#pragma unroll
        for (int cbp = 0; cbp < 2; ++cbp) {
            // 9 taps x 2 ct weight frags (L2-hot, identical across blocks)
            bf16x8 wf[9][2];
#pragma unroll
            for (int q = 0; q < 9; ++q) {
                const size_t base = (size_t)(((zr * 9 + q) * 2 + cbp) * 2) * 512 + lane * 8;
                wf[q][0] = *(const bf16x8*)(wpk + base);
                wf[q][1] = *(const bf16x8*)(wpk + base + 512);
            }
            const unsigned cc = (unsigned)(cbp * 2 + h);
#pragma unroll
            for (int t = 0; t < 4; ++t) {
                const unsigned rowb = (unsigned)zr * SLAB_B + (unsigned)(2 * wy + t) * ROW_B;
                bf16x8 bf[3];
#pragma unroll
                for (int kx = 0; kx < 3; ++kx) {
                    const unsigned sx = (unsigned)(xoff + u + kx);
                    const unsigned k = ((sx - 1u) >> 1) & 3u;
                    bf[kx] = *(const bf16x8*)&lds[rowb + sx * 64u + ((cc ^ k) << 4)];
                }
#pragma unroll
                for (int kx = 0; kx < 3; ++kx) {
                    if (t <= 2) {   // ly=0, ky=t
                        acc[0][0] = __builtin_amdgcn_mfma_f32_32x32x16_bf16(
                            wf[t * 3 + kx][0], bf[kx], acc[0][0], 0, 0, 0);
                        acc[0][1] = __builtin_amdgcn_mfma_f32_32x32x16_bf16(
                            wf[t * 3 + kx][1], bf[kx], acc[0][1], 0, 0, 0);
                    }
                    if (t >= 1) {   // ly=1, ky=t-1
                        acc[1][0] = __builtin_amdgcn_mfma_f32_32x32x16_bf16(
                            wf[(t - 1) * 3 + kx][0], bf[kx], acc[1][0], 0, 0, 0);
                        acc[1][1] = __builtin_amdgcn_mfma_f32_32x32x16_bf16(
                            wf[(t - 1) * 3 + kx][1], bf[kx], acc[1][1], 0, 0, 0);
                    }
                }
            }
        }
    }

    // ---- epilogue: +bias, x mask, store. C: col = u (x), row = (r&3)+8*(r>>2)+4*h (co) ----
    const int ya = y0 + 2 * wy;
    const size_t mb = (((size_t)b * DD + z) * DD + ya) * DD + xoff + u;
    const float m0 = mask[mb]      ? 1.0f : 0.0f;
    const float m1 = mask[mb + DD] ? 1.0f : 0.0f;
#pragma unroll
    for (int r = 0; r < 16; ++r) {
#pragma unroll
        for (int ct = 0; ct < 2; ++ct) {
            const int co = ct * 32 + (r & 3) + 8 * (r >> 2) + 4 * h;
            const float bs = bias[co];
            const size_t o = (((size_t)(b * COUT + co) * DD + z) * DD + ya) * DD + xoff + u;
            out[o]      = (acc[0][ct][r] + bs) * m0;
            out[o + DD] = (acc[1][ct][r] + bs) * m1;
        }
    }
}

// ---------------- fp32 fallback (ws too small) ----------------
#define CI_BLK 16
__global__ __launch_bounds__(256, 2)
void sparse_conv3d_f32(const float* __restrict__ x,
                       const int* __restrict__ mask,
                       const float* __restrict__ weight,
                       const float* __restrict__ bias,
                       float* __restrict__ out) {
    __shared__ float lds[9 * CI_BLK * 66];
    const int y = blockIdx.x, z = blockIdx.y, b = blockIdx.z;
    const int lane = threadIdx.x & 63;
    const int wave = __builtin_amdgcn_readfirstlane(threadIdx.x >> 6);
    float acc[16];
#pragma unroll
    for (int j = 0; j < 16; ++j) acc[j] = 0.0f;
    const int co0 = wave * 16;
    const float* wbase = weight + (size_t)co0 * (CIN * 27);
    for (int cbl = 0; cbl < 2; ++cbl) {
        if (cbl) __syncthreads();
        for (int i = wave; i < 9 * CI_BLK; i += 4) {
            const int r = i >> 4, ci_l = i & 15;
            const int zz = z + (r / 3) - 1, yy = y + (r % 3) - 1;
            const int ci = cbl * CI_BLK + ci_l;
            float v = 0.0f;
            if (zz >= 0 && zz < DD && yy >= 0 && yy < DD)
                v = x[((((size_t)b * CIN + ci) * DD + zz) * DD + yy) * DD + lane];
            float* row = &lds[(size_t)i * 66];
            row[1 + lane] = v;
            if (lane == 0) { row[0] = 0.0f; row[65] = 0.0f; }
        }
        __syncthreads();
        for (int ci_l = 0; ci_l < CI_BLK; ++ci_l) {
            const int ci = cbl * CI_BLK + ci_l;
#pragma unroll
            for (int kz = 0; kz < 3; ++kz) {
#pragma unroll
                for (int ky = 0; ky < 3; ++ky) {
                    const int r = kz * 3 + ky;
                    const float* xrow = &lds[(size_t)(r * CI_BLK + ci_l) * 66 + lane];
                    const float xv0 = xrow[0], xv1 = xrow[1], xv2 = xrow[2];
                    const float* wp = wbase + ci * 27 + kz * 9 + ky * 3;
#pragma unroll
                    for (int j = 0; j < 16; ++j) {
                        acc[j] += wp[(size_t)j * (CIN * 27) + 0] * xv0
                                + wp[(size_t)j * (CIN * 27) + 1] * xv1
                                + wp[(size_t)j * (CIN * 27) + 2] * xv2;
                    }
                }
            }
        }
    }
    const float m = mask[(((size_t)b * DD + z) * DD + y) * DD + lane] ? 1.0f : 0.0f;
#pragma unroll
    for (int j = 0; j < 16; ++j) {
        const int co = co0 + j;
        out[((((size_t)b * COUT + co) * DD + z) * DD + y) * DD + lane] = (acc[j] + bias[co]) * m;
    }
}
#undef CI_BLK

extern "C" void kernel_launch(void* const* d_in, const int* in_sizes, int n_in,
                              void* d_out, int out_size, void* d_ws, size_t ws_size,
                              hipStream_t stream) {
    const float* x    = (const float*)d_in[0];
    const int*   mask = (const int*)d_in[1];
    const float* w    = (const float*)d_in[2];
    const float* bias = (const float*)d_in[3];
    float*       out  = (float*)d_out;

    if (ws_size < WS_NEEDED) {
        sparse_conv3d_f32<<<dim3(DD, DD, 2), 256, 0, stream>>>(x, mask, w, bias, out);
        return;
    }

    uint16_t* xt  = (uint16_t*)d_ws;
    uint16_t* wpk = (uint16_t*)((char*)d_ws + XT_BYTES);
    uint16_t* zp  = (uint16_t*)((char*)d_ws + XT_BYTES + WPK_BYTES);

    pack_weights<<<(WPK_U16 + (int)(ZP_BYTES / 16) + 255) / 256, 256, 0, stream>>>(w, wpk, (uint4*)zp);
    transpose_x<<<dim3(66, DD, 2), 256, 0, stream>>>(x, xt);
    conv_mfma<<<dim3(16, DD, 2), 256, CONV_LDS, stream>>>(xt, wpk, zp, mask, bias, out);
}

// Round 11
// 92.470 us; speedup vs baseline: 2.2459x; 1.1743x over previous
//
#include <hip/hip_runtime.h>
#include <stdint.h>

// SparseConv3d bf16-MFMA implicit GEMM. B=2, Cin=32, Cout=64, D=64, K=3.
// Round 11: r6 macro-shape (512-thr, 8 waves = ct x xtile x wy, y-quad tile,
//   76KB LDS, 2 blocks/CU = 16 waves) + two measured-cost fixes:
//   (1) oct-major conflict-free layout: xt = [b][z][ci_oct(4)][yy(66)][sx(66)]x16B.
//       Wave B-reads are contiguous 512B windows per 32-lane half -> zero bank
//       conflicts (was 4 extra cyc/read = ~27.6k cyc/CU-gen), no swizzle VALU.
//   (2) wave = 2y x 32x x 32co (1 ct) -> 54KB weight L2 traffic per wave
//       (r10's 2-ct waves paid 108KB). Weight L2 was ~31k cyc/CU-gen.
//   Plus bf double-buffer across t (ds latency hidden under MFMAs).

#define DD 64
#define CIN 32
#define COUT 64

typedef __bf16 bf16x8 __attribute__((ext_vector_type(8)));
typedef float f32x16 __attribute__((ext_vector_type(16)));

#define ROW_B_    1056u                                 // 66 sx * 16B
#define OCT_B     6336u                                 // 6 rows * 1056
#define SLAB_B    25344u                                // 4 octs * 6336 (one z-plane)
#define PLANE_OCT (66u * ROW_B_)                        // 69,696 B (one oct, full plane)
#define XT_BYTES  ((size_t)2 * 64 * 4 * 66 * ROW_B_)    // 35,684,352
#define WPK_U16   (27 * 2 * 2 * 64 * 8)                 // 55,296
#define WPK_BYTES ((size_t)WPK_U16 * 2)
#define ZP_BYTES  ((size_t)SLAB_B)
#define WS_NEEDED (XT_BYTES + WPK_BYTES + ZP_BYTES)
#define CONV_LDS  (3 * 25344)                           // 76,032 B

__device__ __forceinline__ uint16_t f2bf(float f) {
    uint32_t u = __builtin_bit_cast(uint32_t, f);
    u += 0x7fffu + ((u >> 16) & 1u);   // RNE
    return (uint16_t)(u >> 16);
}

__device__ __forceinline__ void gll16(const void* g, void* l) {
    __builtin_amdgcn_global_load_lds(
        (__attribute__((address_space(1))) void*)g,
        (__attribute__((address_space(3))) void*)l, 16, 0, 0);
}

// ---------------- pre-kernel 1: weight pack + zero slab ----------------
// wpk flat: (((k27*2 + cb)*2 + ct)*64 + lane)*8 + j
//   lane holds A[co = ct*32 + (lane&31)][ci = cb*16 + (lane>>5)*8 + j]
__global__ void pack_weights(const float* __restrict__ w, uint16_t* __restrict__ wpk,
                             uint4* __restrict__ zp) {
    int flat = blockIdx.x * 256 + threadIdx.x;
    if (flat < WPK_U16) {
        int j   = flat & 7;
        int l   = (flat >> 3) & 63;
        int ct  = (flat >> 9) & 1;
        int cb  = (flat >> 10) & 1;
        int k27 = flat >> 11;
        int co = ct * 32 + (l & 31);
        int ci = cb * 16 + ((l >> 5) * 8) + j;
        wpk[flat] = f2bf(w[(co * CIN + ci) * 27 + k27]);
    } else if (flat - WPK_U16 < (int)(ZP_BYTES / 16)) {
        zp[flat - WPK_U16] = make_uint4(0, 0, 0, 0);
    }
}

// ---------------- pre-kernel 2: x -> oct-major padded channel-last bf16 ----------------
// xt[b][z][oct][yy(66 padded)][sx(66 padded)] of 16B (8 bf16, ci = oct*8 + j).
// yy = 0/65 zero rows; sx = 0/65 zero slots; interior sx = x+1.
__global__ __launch_bounds__(256)
void transpose_x(const float* __restrict__ x, uint16_t* __restrict__ xt) {
    __shared__ uint16_t tile[4 * 66 * 8];   // [oct][sx][j] = 4224 B
    const int yy = blockIdx.x, z = blockIdx.y, b = blockIdx.z;
    const int y = yy - 1;
    const int t = threadIdx.x;
    // 4 destination segments (one per oct), each 66 uint4
    uint4* dst0 = (uint4*)(xt + ((((size_t)(b * DD + z)) * 4 + 0) * 66 + yy) * (ROW_B_ / 2));
    const size_t oct_stride4 = PLANE_OCT / 16;   // uint4 elems per oct-plane

    if (y < 0 || y >= DD) {
        for (int i = t; i < 264; i += 256)
            dst0[(i / 66) * oct_stride4 + (i % 66)] = make_uint4(0, 0, 0, 0);
        return;
    }
    const int ci = t >> 3;
    const int xs = (t & 7) * 8;
    const float* src = x + ((((size_t)b * CIN + ci) * DD + z) * DD + y) * DD + xs;
    float4 v0 = *(const float4*)src;
    float4 v1 = *(const float4*)(src + 4);
    float vals[8] = {v0.x, v0.y, v0.z, v0.w, v1.x, v1.y, v1.z, v1.w};
    const int oct = ci >> 3, j = ci & 7;
#pragma unroll
    for (int e = 0; e < 8; ++e)
        tile[(oct * 66 + (xs + e + 1)) * 8 + j] = f2bf(vals[e]);
    if (t < 64) {   // zero sx=0 and sx=65 slots
        const int o2 = t >> 4, s2 = ((t >> 3) & 1) ? 65 : 0, j2 = t & 7;
        tile[(o2 * 66 + s2) * 8 + j2] = 0;
    }
    __syncthreads();
    const uint4* t4 = (const uint4*)tile;
    for (int i = t; i < 264; i += 256)
        dst0[(i / 66) * oct_stride4 + (i % 66)] = t4[i];
}

// ---------------- main kernel ----------------
// grid (16 yq, 64 z, 2 b) x 512 thr = 8 waves: ct = w&1, xtile = (w>>1)&1, wy = w>>2.
// Wave: 2y x 32x x 32co. Per phase (zr,cb): 9 wf loads, 12 ds_read, 18 MFMA.
__global__ __launch_bounds__(512, 4)
void conv_mfma(const uint16_t* __restrict__ xt, const uint16_t* __restrict__ wpk,
               const uint16_t* __restrict__ zp,
               const int* __restrict__ mask, const float* __restrict__ bias,
               float* __restrict__ out) {
    extern __shared__ __align__(16) unsigned char lds[];   // [zr(3)][oct(4)][row(6)][sx(66)]x16B
    const int yq = blockIdx.x, z = blockIdx.y, b = blockIdx.z;
    const int y0 = yq * 4;
    const int tid = threadIdx.x;
    const int lane = tid & 63;
    const int w = __builtin_amdgcn_readfirstlane(tid >> 6);
    const int ct    = w & 1;
    const int xtile = (w >> 1) & 1;
    const int wy    = w >> 2;
    const int u = lane & 31;
    const int h = lane >> 5;
    const int xoff = xtile * 32;

    // ---- stage 12 runs (zr x oct), each 6336 B contiguous; OOB z -> zero slab ----
    for (int r = w; r < 12; r += 8) {
        const int zr = r >> 2, oct = r & 3;
        const int zz = z - 1 + zr;
        const char* g = (zz >= 0 && zz < DD)
            ? (const char*)xt + ((((size_t)(b * DD + zz)) * 4 + oct) * 66 + y0) * ROW_B_
            : (const char*)zp + oct * OCT_B;
        const unsigned l = (unsigned)(zr * SLAB_B + oct * OCT_B);
#pragma unroll
        for (int c = 0; c < 6; ++c)
            gll16(g + c * 1024 + lane * 16, &lds[l + (unsigned)c * 1024u]);
        if (lane < 12) gll16(g + 6144 + lane * 16, &lds[l + 6144u]);
    }
    __syncthreads();

    f32x16 acc0 = {}, acc1 = {};   // y = y0+2wy, y0+2wy+1

#pragma unroll
    for (int zr = 0; zr < 3; ++zr) {
#pragma unroll
        for (int cbp = 0; cbp < 2; ++cbp) {
            // 9 weight frags for (zr, cb, ct) -> VGPRs (L2/L1-hot)
            bf16x8 wf[9];
#pragma unroll
            for (int q = 0; q < 9; ++q)
                wf[q] = *(const bf16x8*)(wpk
                    + (size_t)(((zr * 9 + q) * 2 + cbp) * 2 + ct) * 512 + lane * 8);
            // base for this wave's oct (cb,h) in slab zr
            const unsigned ob = (unsigned)(zr * SLAB_B + (cbp * 2 + h) * OCT_B)
                              + (unsigned)(xoff + u) * 16u;
            // bf double-buffer across t
            bf16x8 bfc[3], bfn[3];
#pragma unroll
            for (int kx = 0; kx < 3; ++kx)
                bfc[kx] = *(const bf16x8*)&lds[ob + (unsigned)(2 * wy + 0) * ROW_B_ + kx * 16u];
#pragma unroll
            for (int t = 0; t < 4; ++t) {
                if (t < 3) {
#pragma unroll
                    for (int kx = 0; kx < 3; ++kx)
                        bfn[kx] = *(const bf16x8*)&lds[ob + (unsigned)(2 * wy + t + 1) * ROW_B_ + kx * 16u];
                }
#pragma unroll
                for (int kx = 0; kx < 3; ++kx) {
                    if (t <= 2)   // ly=0, ky=t
                        acc0 = __builtin_amdgcn_mfma_f32_32x32x16_bf16(
                            wf[t * 3 + kx], bfc[kx], acc0, 0, 0, 0);
                    if (t >= 1)   // ly=1, ky=t-1
                        acc1 = __builtin_amdgcn_mfma_f32_32x32x16_bf16(
                            wf[(t - 1) * 3 + kx], bfc[kx], acc1, 0, 0, 0);
                }
#pragma unroll
                for (int kx = 0; kx < 3; ++kx) bfc[kx] = bfn[kx];
            }
        }
    }

    // ---- epilogue: +bias, x mask, store. C: col = u (x), row = (r&3)+8*(r>>2)+4*h (co) ----
    const int ya = y0 + 2 * wy;
    const size_t mb = (((size_t)b * DD + z) * DD + ya) * DD + xoff + u;
    const float m0 = mask[mb]      ? 1.0f : 0.0f;
    const float m1 = mask[mb + DD] ? 1.0f : 0.0f;
#pragma unroll
    for (int r = 0; r < 16; ++r) {
        const int co = ct * 32 + (r & 3) + 8 * (r >> 2) + 4 * h;
        const float bs = bias[co];
        const size_t o = (((size_t)(b * COUT + co) * DD + z) * DD + ya) * DD + xoff + u;
        out[o]      = (acc0[r] + bs) * m0;
        out[o + DD] = (acc1[r] + bs) * m1;
    }
}

// ---------------- fp32 fallback (ws too small) ----------------
#define CI_BLK 16
__global__ __launch_bounds__(256, 2)
void sparse_conv3d_f32(const float* __restrict__ x,
                       const int* __restrict__ mask,
                       const float* __restrict__ weight,
                       const float* __restrict__ bias,
                       float* __restrict__ out) {
    __shared__ float lds[9 * CI_BLK * 66];
    const int y = blockIdx.x, z = blockIdx.y, b = blockIdx.z;
    const int lane = threadIdx.x & 63;
    const int wave = __builtin_amdgcn_readfirstlane(threadIdx.x >> 6);
    float acc[16];
#pragma unroll
    for (int j = 0; j < 16; ++j) acc[j] = 0.0f;
    const int co0 = wave * 16;
    const float* wbase = weight + (size_t)co0 * (CIN * 27);
    for (int cbl = 0; cbl < 2; ++cbl) {
        if (cbl) __syncthreads();
        for (int i = wave; i < 9 * CI_BLK; i += 4) {
            const int r = i >> 4, ci_l = i & 15;
            const int zz = z + (r / 3) - 1, yy = y + (r % 3) - 1;
            const int ci = cbl * CI_BLK + ci_l;
            float v = 0.0f;
            if (zz >= 0 && zz < DD && yy >= 0 && yy < DD)
                v = x[((((size_t)b * CIN + ci) * DD + zz) * DD + yy) * DD + lane];
            float* row = &lds[(size_t)i * 66];
            row[1 + lane] = v;
            if (lane == 0) { row[0] = 0.0f; row[65] = 0.0f; }
        }
        __syncthreads();
        for (int ci_l = 0; ci_l < CI_BLK; ++ci_l) {
            const int ci = cbl * CI_BLK + ci_l;
#pragma unroll
            for (int kz = 0; kz < 3; ++kz) {
#pragma unroll
                for (int ky = 0; ky < 3; ++ky) {
                    const int r = kz * 3 + ky;
                    const float* xrow = &lds[(size_t)(r * CI_BLK + ci_l) * 66 + lane];
                    const float xv0 = xrow[0], xv1 = xrow[1], xv2 = xrow[2];
                    const float* wp = wbase + ci * 27 + kz * 9 + ky * 3;
#pragma unroll
                    for (int j = 0; j < 16; ++j) {
                        acc[j] += wp[(size_t)j * (CIN * 27) + 0] * xv0
                                + wp[(size_t)j * (CIN * 27) + 1] * xv1
                                + wp[(size_t)j * (CIN * 27) + 2] * xv2;
                    }
                }
            }
        }
    }
    const float m = mask[(((size_t)b * DD + z) * DD + y) * DD + lane] ? 1.0f : 0.0f;
#pragma unroll
    for (int j = 0; j < 16; ++j) {
        const int co = co0 + j;
        out[((((size_t)b * COUT + co) * DD + z) * DD + y) * DD + lane] = (acc[j] + bias[co]) * m;
    }
}
#undef CI_BLK

extern "C" void kernel_launch(void* const* d_in, const int* in_sizes, int n_in,
                              void* d_out, int out_size, void* d_ws, size_t ws_size,
                              hipStream_t stream) {
    const float* x    = (const float*)d_in[0];
    const int*   mask = (const int*)d_in[1];
    const float* w    = (const float*)d_in[2];
    const float* bias = (const float*)d_in[3];
    float*       out  = (float*)d_out;

    if (ws_size < WS_NEEDED) {
        sparse_conv3d_f32<<<dim3(DD, DD, 2), 256, 0, stream>>>(x, mask, w, bias, out);
        return;
    }

    uint16_t* xt  = (uint16_t*)d_ws;
    uint16_t* wpk = (uint16_t*)((char*)d_ws + XT_BYTES);
    uint16_t* zp  = (uint16_t*)((char*)d_ws + XT_BYTES + WPK_BYTES);

    pack_weights<<<(WPK_U16 + (int)(ZP_BYTES / 16) + 255) / 256, 256, 0, stream>>>(w, wpk, (uint4*)zp);
    transpose_x<<<dim3(66, DD, 2), 256, 0, stream>>>(x, xt);
    conv_mfma<<<dim3(16, DD, 2), 512, CONV_LDS, stream>>>(xt, wpk, zp, mask, bias, out);
}